// Round 9
// baseline (270.036 us; speedup 1.0000x reference)
//
#include <hip/hip_runtime.h>

// FeatureMatchSimpleLoss: B=128, P=512, D=384, GAMMA=20, LAMBDA_INV=25
// R9: SINGLE persistent kernel (512 blocks, all-resident by construction:
// 50KB LDS + launch_bounds(256,2) -> >=2 blocks/CU -> capacity >= 512).
// Phases separated by device-scope grid syncs (atomic counter + spin +
// __threadfence for cross-XCD L2 coherence). Removes ~3 launch edges
// (~10-12us each) that dominated after R8.
//   phase 0: convert z fp32 -> zt[b][kt][kg][p][8] bf16 (coalesced both sides)
//   phase 1: gemm, 2-3 upper-tri 128x128 tiles per block (R8 body: depth-2
//            pipeline, 3 LDS bufs, 1 barrier/k-step, counted vmcnt)
//   phase 2: blocks 0..63: combine 4 partials + local top-20 -> cval/cidx
//   phase 3: block 0: merge 1280 -> top-20 -> best-j -> loss + avg_cos
// Counters in d_ws zeroed per call via hipMemsetAsync (graph-capturable).

#define NB 128
#define NP 512
#define ND 384
#define NGAMMA 20
#define NKS 12      // 384/32 k-steps
#define GRID 512
#define NTILE 1280  // NB * 10 upper-tri tiles

typedef __attribute__((ext_vector_type(8))) short short8;
typedef __attribute__((ext_vector_type(4))) float f32x4;

__device__ __forceinline__ unsigned short f2bf(float f) {
    unsigned int u = __float_as_uint(f);
    u += 0x7fffu + ((u >> 16) & 1u);   // RNE
    return (unsigned short)(u >> 16);
}

__device__ __forceinline__ void gload16(const void* gptr, void* lptr) {
    __builtin_amdgcn_global_load_lds(
        (const __attribute__((address_space(1))) void*)gptr,
        (__attribute__((address_space(3))) void*)lptr, 16, 0, 0);
}

// device-scope grid sync: release = syncthreads(vmcnt drain) + fence + add;
// acquire = spin + fence (threadfence emits L2 wb/inv -> cross-XCD safe).
__device__ __forceinline__ void grid_sync(int* cnt, int target) {
    __syncthreads();
    if (threadIdx.x == 0) {
        __threadfence();
        __hip_atomic_fetch_add(cnt, 1, __ATOMIC_RELEASE, __HIP_MEMORY_SCOPE_AGENT);
        while (__hip_atomic_load(cnt, __ATOMIC_RELAXED, __HIP_MEMORY_SCOPE_AGENT) < target)
            __builtin_amdgcn_s_sleep(2);
        __threadfence();
    }
    __syncthreads();
}

__global__ __launch_bounds__(256, 2) void fm_fused(
    const float* __restrict__ z, const int* __restrict__ view,
    unsigned short* __restrict__ zt,
    float* __restrict__ pval, int* __restrict__ pidx,
    float* __restrict__ cval, int* __restrict__ cidx,
    int* __restrict__ cnt, float* __restrict__ out)
{
    __shared__ __align__(16) char lds[51200];
    // gemm views
    unsigned short (*Ah)[4][128][8] = (unsigned short(*)[4][128][8])lds;           // 3 x 8KB
    unsigned short (*Bh)[4][128][8] = (unsigned short(*)[4][128][8])(lds + 24576); // 3 x 8KB
    int* vs = (int*)(lds + 49152);                                                 // 2KB

    const int tid  = threadIdx.x;
    const int bid  = blockIdx.x;
    const int lane = tid & 63;
    const int wid  = tid >> 6;
    const int wr   = wid >> 1, wc = wid & 1;
    const int g    = lane >> 4, r = lane & 15;

    // ================= phase 0: convert z -> zt (12 tasks/block) =============
    {
        float (*ls)[36] = (float(*)[36])lds;   // 128 x 36 fp32 = 18KB
        for (int i = 0; i < 12; ++i) {
            const int task = bid * 12 + i;               // 0..6143
            const int b    = task / (NKS * 4);
            const int rem  = task % (NKS * 4);
            const int kt   = rem >> 2;
            const int pblk = rem & 3;
            const float* zsrc = z + ((size_t)b * NP + pblk * 128) * ND + kt * 32;
#pragma unroll
            for (int k = 0; k < 4; ++k) {
                const int f = tid + k * 256, row = f >> 3, c4 = f & 7;
                *(float4*)&ls[row][c4 * 4] =
                    *(const float4*)(zsrc + (size_t)row * ND + c4 * 4);
            }
            __syncthreads();
            const int kg = wid;   // wave = kg plane
            unsigned short* dst = zt + (((size_t)b * NKS + kt) * 4 + kg) * 4096
                                     + (size_t)pblk * 1024;
#pragma unroll
            for (int it = 0; it < 2; ++it) {
                const int row = it * 64 + lane;
                const float4 v0 = *(const float4*)&ls[row][kg * 8];
                const float4 v1 = *(const float4*)&ls[row][kg * 8 + 4];
                short8 s;
                s[0] = (short)f2bf(v0.x); s[1] = (short)f2bf(v0.y);
                s[2] = (short)f2bf(v0.z); s[3] = (short)f2bf(v0.w);
                s[4] = (short)f2bf(v1.x); s[5] = (short)f2bf(v1.y);
                s[6] = (short)f2bf(v1.z); s[7] = (short)f2bf(v1.w);
                *(short8*)(dst + (size_t)row * 8) = s;
            }
            __syncthreads();
        }
    }
    grid_sync(cnt + 0, GRID);

    // ================= phase 1: gemm, 2-3 tiles per block =====================
    vs[tid]       = view[tid];
    vs[tid + 256] = view[tid + 256];
    // epilogue scratch aliased onto Ah[0] (dead: kt=11 barrier implies all
    // waves finished COMPUTE(9), the last reader of buf 0)
    float* lsv = (float*)lds;
    int*   lsi = (int*)lds + 256;
    float* lqv = (float*)lds + 512;
    int*   lqi = (int*)lds + 768;

#define STAGE(BUF, KT, P0, Q0, BB)                                               \
    do {                                                                         \
        _Pragma("unroll")                                                        \
        for (int i_ = 0; i_ < 2; ++i_) {                                         \
            const int c_  = wid * 2 + i_;                                        \
            const int kg_ = c_ >> 1;                                             \
            const int rb_ = (c_ & 1) * 64;                                       \
            const size_t pl_ = (((size_t)(BB) * NKS + (KT)) * 4 + kg_) * 4096;   \
            gload16(zt + pl_ + (size_t)((P0) + rb_ + lane) * 8,                  \
                    &Ah[BUF][kg_][rb_][0]);                                      \
            gload16(zt + pl_ + (size_t)((Q0) + rb_ + lane) * 8,                  \
                    &Bh[BUF][kg_][rb_][0]);                                      \
        }                                                                        \
    } while (0)

#define COMPUTE(BUF)                                                             \
    do {                                                                         \
        short8 ah_[4], bh_[4];                                                   \
        _Pragma("unroll")                                                        \
        for (int mi = 0; mi < 4; ++mi)                                           \
            ah_[mi] = *(const short8*)&Ah[BUF][g][wr * 64 + mi * 16 + r][0];     \
        _Pragma("unroll")                                                        \
        for (int ni = 0; ni < 4; ++ni)                                           \
            bh_[ni] = *(const short8*)&Bh[BUF][g][wc * 64 + ni * 16 + r][0];     \
        _Pragma("unroll")                                                        \
        for (int mi = 0; mi < 4; ++mi)                                           \
            _Pragma("unroll")                                                    \
            for (int ni = 0; ni < 4; ++ni)                                       \
                acc[mi][ni] = __builtin_amdgcn_mfma_f32_16x16x32_bf16(           \
                    ah_[mi], bh_[ni], acc[mi][ni], 0, 0, 0);                     \
    } while (0)

    for (int pass = 0; pass < 3; ++pass) {
        const int x = bid + pass * 512;
        if (x >= NTILE) break;
        // XCD swizzle (bijective over the union of passes)
        const int gidx = (x & 7) * 160 + (x >> 3);   // 0..1279
        const int b    = gidx / 10;
        const int t    = gidx % 10;
        int tr, tc;
        if (t < 4)      { tr = 0; tc = t; }
        else if (t < 7) { tr = 1; tc = t - 3; }
        else if (t < 9) { tr = 2; tc = t - 5; }
        else            { tr = 3; tc = 3; }
        const bool diag = (tr == tc);
        const int p0 = tr * 128, q0 = tc * 128;

        f32x4 acc[4][4];
#pragma unroll
        for (int mi = 0; mi < 4; ++mi)
#pragma unroll
            for (int ni = 0; ni < 4; ++ni) acc[mi][ni] = (f32x4){0.f, 0.f, 0.f, 0.f};

        __syncthreads();   // prev tile's epilogue scratch reads done; vs visible
        STAGE(0, 0, p0, q0, b);
        STAGE(1, 1, p0, q0, b);
#pragma unroll
        for (int kt = 0; kt < NKS; ++kt) {
            // steady state: tiles kt + kt+1 in flight (4 loads each).
            if (kt < NKS - 1) asm volatile("s_waitcnt vmcnt(4)" ::: "memory");
            else              asm volatile("s_waitcnt vmcnt(0)" ::: "memory");
            __builtin_amdgcn_s_barrier();      // tile kt resident everywhere;
                                               // compute(kt-1) done -> STAGE
                                               // target buffer free
            __builtin_amdgcn_sched_barrier(0);
            if (kt + 2 < NKS) STAGE((kt + 2) % 3, kt + 2, p0, q0, b);
            __builtin_amdgcn_sched_barrier(0); // stage issues before compute
            COMPUTE(kt % 3);
        }

        // ---- row-side: per row p, masked max/argmax over 128 cols ----
        // C/D layout: col = lane&15 (r), row = (lane>>4)*4 + j (g,j)
#pragma unroll
        for (int mi = 0; mi < 4; ++mi) {
#pragma unroll
            for (int j = 0; j < 4; ++j) {
                const int prow = p0 + wr * 64 + mi * 16 + g * 4 + j;
                const int rv = vs[prow];
                float bv = -2.0f; int bq = 0;
#pragma unroll
                for (int ni = 0; ni < 4; ++ni) {   // ascending q; strict >
                    const int q = q0 + wc * 64 + ni * 16 + r;
                    const float v = (vs[q] != rv) ? acc[mi][ni][j] : -1.0f;
                    if (v > bv) { bv = v; bq = q; }
                }
#pragma unroll
                for (int off = 1; off < 16; off <<= 1) {
                    const float ov = __shfl_xor(bv, off);
                    const int   oq = __shfl_xor(bq, off);
                    if (ov > bv || (ov == bv && oq < bq)) { bv = ov; bq = oq; }
                }
                if (r == 0) {
                    lsv[(wr * 2 + wc) * 64 + mi * 16 + g * 4 + j] = bv;
                    lsi[(wr * 2 + wc) * 64 + mi * 16 + g * 4 + j] = bq;
                }
            }
        }
        // ---- col-side (off-diag only) ----
        if (!diag) {
#pragma unroll
            for (int ni = 0; ni < 4; ++ni) {
                const int q = q0 + wc * 64 + ni * 16 + r;
                const int qv = vs[q];
                float bv = -2.0f; int bp = 0;
#pragma unroll
                for (int mi = 0; mi < 4; ++mi)
#pragma unroll
                    for (int j = 0; j < 4; ++j) {   // ascending p within g
                        const int prow = p0 + wr * 64 + mi * 16 + g * 4 + j;
                        const float v = (vs[prow] != qv) ? acc[mi][ni][j] : -1.0f;
                        if (v > bv) { bv = v; bp = prow; }
                    }
#pragma unroll
                for (int off = 16; off < 64; off <<= 1) {
                    const float ov = __shfl_xor(bv, off);
                    const int   op = __shfl_xor(bp, off);
                    if (ov > bv || (ov == bv && op < bp)) { bv = ov; bp = op; }
                }
                if (g == 0) {
                    lqv[(wc * 2 + wr) * 64 + ni * 16 + r] = bv;
                    lqi[(wc * 2 + wr) * 64 + ni * 16 + r] = bp;
                }
            }
        }
        __syncthreads();
        if (tid < 128) {
            const int half = tid >> 6, row = tid & 63;
            {
                float v0 = lsv[(half * 2 + 0) * 64 + row]; int i0 = lsi[(half * 2 + 0) * 64 + row];
                const float v1 = lsv[(half * 2 + 1) * 64 + row]; const int i1 = lsi[(half * 2 + 1) * 64 + row];
                if (v1 > v0) { v0 = v1; i0 = i1; }   // tie keeps smaller q
                const int p = p0 + half * 64 + row;
                pval[((size_t)b * NP + p) * 4 + tc] = v0;
                pidx[((size_t)b * NP + p) * 4 + tc] = i0;
            }
            if (!diag) {
                float v0 = lqv[(half * 2 + 0) * 64 + row]; int i0 = lqi[(half * 2 + 0) * 64 + row];
                const float v1 = lqv[(half * 2 + 1) * 64 + row]; const int i1 = lqi[(half * 2 + 1) * 64 + row];
                if (v1 > v0) { v0 = v1; i0 = i1; }   // tie keeps smaller p
                const int q = q0 + half * 64 + row;
                pval[((size_t)b * NP + q) * 4 + tr] = v0;
                pidx[((size_t)b * NP + q) * 4 + tr] = i0;
            }
        }
    }
#undef STAGE
#undef COMPUTE
    grid_sync(cnt + 1, GRID);

    if (bid >= 64) return;

    // ================= phase 2: blocks 0..63 local top-20 =====================
    {
        float* sv = (float*)lds;              // 1024 floats
        float* wv = (float*)(lds + 4096);     // 4
        int*   wi = (int*)(lds + 4112);       // 4
        const int base = bid * 1024;
#pragma unroll
        for (int i = 0; i < 4; ++i) {
            const int e = tid + 256 * i;
            const float4 pv = ((const float4*)pval)[base + e];
            float bv = pv.x;                  // ascending c; strict > keeps first
            if (pv.y > bv) bv = pv.y;
            if (pv.z > bv) bv = pv.z;
            if (pv.w > bv) bv = pv.w;
            sv[e] = bv;
        }
        __syncthreads();
        for (int it = 0; it < NGAMMA; ++it) {
            float v = sv[tid];
            int pos = tid;
#pragma unroll
            for (int i = 1; i < 4; ++i) {
                const int e = tid + 256 * i;
                const float x2 = sv[e];
                if (x2 > v || (x2 == v && e < pos)) { v = x2; pos = e; }
            }
#pragma unroll
            for (int off = 1; off < 64; off <<= 1) {
                const float ov = __shfl_xor(v, off);
                const int   op = __shfl_xor(pos, off);
                if (ov > v || (ov == v && op < pos)) { v = ov; pos = op; }
            }
            if (lane == 0) { wv[wid] = v; wi[wid] = pos; }
            __syncthreads();
            if (tid == 0) {
                float bv2 = wv[0]; int bp = wi[0];
                for (int k = 1; k < 4; ++k)
                    if (wv[k] > bv2 || (wv[k] == bv2 && wi[k] < bp)) { bv2 = wv[k]; bp = wi[k]; }
                cval[bid * NGAMMA + it] = bv2;
                cidx[bid * NGAMMA + it] = base + bp;
                sv[bp] = -1e30f;
            }
            __syncthreads();
        }
        __syncthreads();
        if (tid == 0) {
            __threadfence();
            __hip_atomic_fetch_add(cnt + 2, 1, __ATOMIC_RELEASE, __HIP_MEMORY_SCOPE_AGENT);
        }
    }
    if (bid != 0) return;

    // ================= phase 3: block 0 final merge + loss ====================
    if (tid == 0) {
        while (__hip_atomic_load(cnt + 2, __ATOMIC_RELAXED, __HIP_MEMORY_SCOPE_AGENT) < 64)
            __builtin_amdgcn_s_sleep(2);
        __threadfence();
    }
    __syncthreads();

    int*   sel  = (int*)(lds + 8192);
    int*   selj = (int*)(lds + 8192 + 128);
    float* red  = (float*)(lds + 8192 + 256);
    float ssum = 0.f;

    if (wid == 0) {
        float v[20]; int id[20];
#pragma unroll
        for (int i = 0; i < 20; ++i) {
            const int e = i * 64 + lane;
            v[i] = cval[e]; id[i] = cidx[e];
        }
        for (int it = 0; it < NGAMMA; ++it) {
            float bv = v[0]; int bi = id[0];
#pragma unroll
            for (int i = 1; i < 20; ++i)
                if (v[i] > bv || (v[i] == bv && id[i] < bi)) { bv = v[i]; bi = id[i]; }
#pragma unroll
            for (int off = 1; off < 64; off <<= 1) {
                const float ov = __shfl_xor(bv, off);
                const int   oi = __shfl_xor(bi, off);
                if (ov > bv || (ov == bv && oi < bi)) { bv = ov; bi = oi; }
            }
            if (lane == 0) sel[it] = bi;
            ssum += bv;
#pragma unroll
            for (int i = 0; i < 20; ++i) if (id[i] == bi) v[i] = -1e30f;
        }
        // best-j for the 20 selected anchors (argmax over 4 partials)
        if (lane < NGAMMA) {
            const int a = sel[lane];   // lane0-written; same-wave LDS ordered
            const float4 pv = ((const float4*)pval)[a];
            float bv = pv.x; int bc = 0;       // ascending c = ascending q-block
            if (pv.y > bv) { bv = pv.y; bc = 1; }
            if (pv.z > bv) { bv = pv.z; bc = 2; }
            if (pv.w > bv) { bv = pv.w; bc = 3; }
            selj[lane] = ((a >> 9) << 9) + pidx[(size_t)a * 4 + bc];
        }
    }
    __syncthreads();

    // loss = 25 * mean((z1 - z2)^2) over 20 x 384 (exact fp32 z)
    float acc2 = 0.f;
    for (int pr = 0; pr < NGAMMA; ++pr) {
        const int a = sel[pr];
        const int j = selj[pr];
        const float* za = z + (size_t)a * ND;
        const float* zj = z + (size_t)j * ND;
        for (int d = tid; d < ND; d += 256) {
            const float df = za[d] - zj[d];
            acc2 = fmaf(df, df, acc2);
        }
    }
#pragma unroll
    for (int off = 1; off < 64; off <<= 1) acc2 += __shfl_xor(acc2, off);
    if (lane == 0) red[wid] = acc2;
    __syncthreads();
    if (tid == 0) {
        const float tot = red[0] + red[1] + red[2] + red[3];
        out[0] = 25.0f * tot / (float)(NGAMMA * ND);
        out[1] = ssum / (float)NGAMMA;   // tid0 = lane0 of wave0: has ssum
    }
}

extern "C" void kernel_launch(void* const* d_in, const int* in_sizes, int n_in,
                              void* d_out, int out_size, void* d_ws, size_t ws_size,
                              hipStream_t stream)
{
    const float* z    = (const float*)d_in[0];
    const int*   view = (const int*)d_in[1];
    float*       out  = (float*)d_out;
    char* ws = (char*)d_ws;

    // layout: zt 48MB | pval 1MB | pidx 1MB | cval 5KB | cidx 5KB | cnt 12B
    const size_t zt_off   = 0;
    const size_t pval_off = (size_t)NB * NP * ND * 2;
    const size_t pidx_off = pval_off + (size_t)NB * NP * 4 * 4;
    const size_t cval_off = pidx_off + (size_t)NB * NP * 4 * 4;
    const size_t cidx_off = cval_off + 64 * NGAMMA * 4;
    const size_t cnt_off  = cidx_off + 64 * NGAMMA * 4;

    unsigned short* zt = (unsigned short*)(ws + zt_off);
    float* pval = (float*)(ws + pval_off);
    int*   pidx = (int*)(ws + pidx_off);
    float* cval = (float*)(ws + cval_off);
    int*   cidx = (int*)(ws + cidx_off);
    int*   cnt  = (int*)(ws + cnt_off);

    hipMemsetAsync(cnt, 0, 3 * sizeof(int), stream);
    fm_fused<<<GRID, 256, 0, stream>>>(z, view, zt, pval, pidx, cval, cidx, cnt, out);
}

// Round 10
// 135.072 us; speedup vs baseline: 1.9992x; 1.9992x over previous
//
#include <hip/hip_runtime.h>

// FeatureMatchSimpleLoss: B=128, P=512, D=384, GAMMA=20, LAMBDA_INV=25
// R10: 4-kernel structure (R9 fusion regressed: grid syncs cost ~200us).
// gemm = BARRIER-FREE direct-register MFMA: fragments loaded straight from
// the pre-tiled zt (R8 layout) -> 256B-contiguous per 16-lane group (~8-16
// cache lines/instr vs R4's 64), no LDS staging, no s_barrier, no vmcnt.
// Every wave runs an independent fully-unrolled 12-step load+MFMA loop;
// ~12 independent waves/CU hide L2 latency via TLP+ILP.
//   fm_convert:    z fp32 -> zt[b][kt][kg][p][8] bf16 (LDS transpose)
//   fm_gemm:       per (b, upper-tri 128x128 tile), fused row+col argmax
//   fm_topk_local: wave-level combine + local top-20
//   fm_final:      wave-level merge 1280 -> top-20 -> best-j -> loss + avg

#define NB 128
#define NP 512
#define ND 384
#define NGAMMA 20
#define NKS 12   // 384/32 k-steps

typedef __attribute__((ext_vector_type(8))) short short8;
typedef __attribute__((ext_vector_type(4))) float f32x4;

__device__ __forceinline__ unsigned short f2bf(float f) {
    unsigned int u = __float_as_uint(f);
    u += 0x7fffu + ((u >> 16) & 1u);   // RNE
    return (unsigned short)(u >> 16);
}

// ---- convert+tile: z fp32 row-major -> zt[b][kt][kg][p 0..511][8] bf16 ----
__global__ __launch_bounds__(256) void fm_convert(
    const float* __restrict__ z, unsigned short* __restrict__ zt)
{
    __shared__ float ls[128][36];   // pad 36: float4 rows 16B-aligned

    const int tid  = threadIdx.x;
    const int bid  = blockIdx.x;
    const int b    = bid / (NKS * 4);
    const int rem  = bid % (NKS * 4);
    const int kt   = rem >> 2;
    const int pblk = rem & 3;

    const float* zsrc = z + ((size_t)b * NP + pblk * 128) * ND + kt * 32;
#pragma unroll
    for (int i = 0; i < 4; ++i) {
        const int f   = tid + i * 256;
        const int row = f >> 3, c4 = f & 7;
        *(float4*)&ls[row][c4 * 4] = *(const float4*)(zsrc + (size_t)row * ND + c4 * 4);
    }
    __syncthreads();

    const int kg = tid >> 6, lane = tid & 63;
    unsigned short* dst = zt + (((size_t)b * NKS + kt) * 4 + kg) * 4096
                             + (size_t)pblk * 1024;
#pragma unroll
    for (int it = 0; it < 2; ++it) {
        const int row = it * 64 + lane;
        const float4 v0 = *(const float4*)&ls[row][kg * 8];
        const float4 v1 = *(const float4*)&ls[row][kg * 8 + 4];
        short8 s;
        s[0] = (short)f2bf(v0.x); s[1] = (short)f2bf(v0.y);
        s[2] = (short)f2bf(v0.z); s[3] = (short)f2bf(v0.w);
        s[4] = (short)f2bf(v1.x); s[5] = (short)f2bf(v1.y);
        s[6] = (short)f2bf(v1.z); s[7] = (short)f2bf(v1.w);
        *(short8*)(dst + (size_t)row * 8) = s;
    }
}

// ---- barrier-free direct-register MFMA GEMM on upper-tri tiles ----
__global__ __launch_bounds__(256, 3) void fm_gemm(
    const unsigned short* __restrict__ zt, const int* __restrict__ view,
    float* __restrict__ pval, int* __restrict__ pidx)
{
    __shared__ int vs[NP];
    __shared__ float lsv[2][2][64];   // row-side [wr][wc][row]
    __shared__ int   lsi[2][2][64];
    __shared__ float lqv[2][2][64];   // col-side [wc][wr][col]
    __shared__ int   lqi[2][2][64];

    const int tid  = threadIdx.x;
    const int lane = tid & 63;
    const int wid  = tid >> 6;
    const int wr   = wid >> 1, wc = wid & 1;
    const int g    = lane >> 4, r = lane & 15;

    // XCD swizzle (1280 % 8 == 0 -> bijective): each XCD gets 16 whole batches
    const int bid  = blockIdx.x;
    const int gidx = (bid & 7) * 160 + (bid >> 3);
    const int b    = gidx / 10;
    const int t    = gidx % 10;
    int tr, tc;
    if (t < 4)      { tr = 0; tc = t; }
    else if (t < 7) { tr = 1; tc = t - 3; }
    else if (t < 9) { tr = 2; tc = t - 5; }
    else            { tr = 3; tc = 3; }
    const bool diag = (tr == tc);
    const int p0 = tr * 128, q0 = tc * 128;

    vs[tid]       = view[tid];
    vs[tid + 256] = view[tid + 256];
    __syncthreads();

    // per-lane fragment bases into zt. Fragment (16x16x32): lane = 16*g + r
    // holds row r, k = g*8..g*8+7 -> 16B contiguous; 16-lane group = 256B run.
    const size_t zbB = (size_t)b * (NKS * 4 * 4096);
    const unsigned short* __restrict__ Az =
        zt + zbB + (size_t)g * 4096 + (size_t)(p0 + wr * 64 + r) * 8;
    const unsigned short* __restrict__ Bz =
        zt + zbB + (size_t)g * 4096 + (size_t)(q0 + wc * 64 + r) * 8;

    f32x4 acc[4][4];
#pragma unroll
    for (int mi = 0; mi < 4; ++mi)
#pragma unroll
        for (int ni = 0; ni < 4; ++ni) acc[mi][ni] = (f32x4){0.f, 0.f, 0.f, 0.f};

#pragma unroll
    for (int kt = 0; kt < NKS; ++kt) {
        short8 ah[4], bh[4];
#pragma unroll
        for (int mi = 0; mi < 4; ++mi)
            ah[mi] = *(const short8*)(Az + (size_t)kt * 16384 + mi * 128);
#pragma unroll
        for (int ni = 0; ni < 4; ++ni)
            bh[ni] = *(const short8*)(Bz + (size_t)kt * 16384 + ni * 128);
#pragma unroll
        for (int mi = 0; mi < 4; ++mi)
#pragma unroll
            for (int ni = 0; ni < 4; ++ni)
                acc[mi][ni] = __builtin_amdgcn_mfma_f32_16x16x32_bf16(
                    ah[mi], bh[ni], acc[mi][ni], 0, 0, 0);
    }

    // ---- row-side: per row p, masked max/argmax over this tile's 128 cols ----
    // C/D layout: col = lane&15 (r), row = (lane>>4)*4 + j (g,j)
#pragma unroll
    for (int mi = 0; mi < 4; ++mi) {
#pragma unroll
        for (int j = 0; j < 4; ++j) {
            const int prow = p0 + wr * 64 + mi * 16 + g * 4 + j;
            const int rv = vs[prow];
            float bv = -2.0f; int bq = 0;
#pragma unroll
            for (int ni = 0; ni < 4; ++ni) {   // ascending q; strict > keeps smallest
                const int q = q0 + wc * 64 + ni * 16 + r;
                const float v = (vs[q] != rv) ? acc[mi][ni][j] : -1.0f;
                if (v > bv) { bv = v; bq = q; }
            }
#pragma unroll
            for (int off = 1; off < 16; off <<= 1) {   // reduce over col-lanes
                const float ov = __shfl_xor(bv, off);
                const int   oq = __shfl_xor(bq, off);
                if (ov > bv || (ov == bv && oq < bq)) { bv = ov; bq = oq; }
            }
            if (r == 0) {
                lsv[wr][wc][mi * 16 + g * 4 + j] = bv;
                lsi[wr][wc][mi * 16 + g * 4 + j] = bq;
            }
        }
    }
    // ---- col-side (off-diag only): per col q, masked max/argmax over 128 rows ----
    if (!diag) {
#pragma unroll
        for (int ni = 0; ni < 4; ++ni) {
            const int q = q0 + wc * 64 + ni * 16 + r;
            const int qv = vs[q];
            float bv = -2.0f; int bp = 0;
#pragma unroll
            for (int mi = 0; mi < 4; ++mi)
#pragma unroll
                for (int j = 0; j < 4; ++j) {   // ascending p within fixed g
                    const int prow = p0 + wr * 64 + mi * 16 + g * 4 + j;
                    const float v = (vs[prow] != qv) ? acc[mi][ni][j] : -1.0f;
                    if (v > bv) { bv = v; bp = prow; }
                }
#pragma unroll
            for (int off = 16; off < 64; off <<= 1) {   // reduce over g groups
                const float ov = __shfl_xor(bv, off);
                const int   op = __shfl_xor(bp, off);
                if (ov > bv || (ov == bv && op < bp)) { bv = ov; bp = op; }
            }
            if (g == 0) {
                lqv[wc][wr][ni * 16 + r] = bv;
                lqi[wc][wr][ni * 16 + r] = bp;
            }
        }
    }
    __syncthreads();
    if (tid < 128) {
        const int half = tid >> 6, row = tid & 63;
        {
            float v0 = lsv[half][0][row]; int i0 = lsi[half][0][row];
            const float v1 = lsv[half][1][row]; const int i1 = lsi[half][1][row];
            if (v1 > v0) { v0 = v1; i0 = i1; }   // tie keeps wc=0 (smaller q)
            const int p = p0 + half * 64 + row;
            pval[((size_t)b * NP + p) * 4 + tc] = v0;
            pidx[((size_t)b * NP + p) * 4 + tc] = i0;
        }
        if (!diag) {
            float v0 = lqv[half][0][row]; int i0 = lqi[half][0][row];
            const float v1 = lqv[half][1][row]; const int i1 = lqi[half][1][row];
            if (v1 > v0) { v0 = v1; i0 = i1; }   // tie keeps wr=0 (smaller p)
            const int q = q0 + half * 64 + row;
            pval[((size_t)b * NP + q) * 4 + tr] = v0;
            pidx[((size_t)b * NP + q) * 4 + tr] = i0;
        }
    }
}

// ---- Phase 2a: wave-level combine + local top-20 over 1024 anchors ----
__global__ __launch_bounds__(64) void fm_topk_local(
    const float* __restrict__ pval, float* __restrict__ cval, int* __restrict__ cidx)
{
    const int lane = threadIdx.x;
    const int base = blockIdx.x * 1024;
    float v[16]; int id[16];
#pragma unroll
    for (int i = 0; i < 16; ++i) {
        const int a = base + i * 64 + lane;
        const float4 pv = ((const float4*)pval)[a];
        float bv = pv.x;                       // ascending c; strict > keeps first
        if (pv.y > bv) bv = pv.y;
        if (pv.z > bv) bv = pv.z;
        if (pv.w > bv) bv = pv.w;
        v[i] = bv; id[i] = a;
    }
    for (int it = 0; it < NGAMMA; ++it) {
        float bv = v[0]; int bi = id[0];
#pragma unroll
        for (int i = 1; i < 16; ++i)
            if (v[i] > bv || (v[i] == bv && id[i] < bi)) { bv = v[i]; bi = id[i]; }
#pragma unroll
        for (int off = 1; off < 64; off <<= 1) {
            const float ov = __shfl_xor(bv, off);
            const int   oi = __shfl_xor(bi, off);
            if (ov > bv || (ov == bv && oi < bi)) { bv = ov; bi = oi; }
        }
        if (lane == 0) {
            cval[blockIdx.x * NGAMMA + it] = bv;
            cidx[blockIdx.x * NGAMMA + it] = bi;
        }
#pragma unroll
        for (int i = 0; i < 16; ++i) if (id[i] == bi) v[i] = -1e30f;
    }
}

// ---- Phase 2b: wave-level merge 1280 -> top-20 -> best-j -> loss + avg ----
__global__ __launch_bounds__(256) void fm_final(
    const float* __restrict__ cval, const int* __restrict__ cidx,
    const float* __restrict__ pval, const int* __restrict__ pidx,
    const float* __restrict__ z, float* __restrict__ out)
{
    __shared__ int sel[NGAMMA];
    __shared__ int selj[NGAMMA];
    __shared__ float red[4];

    const int t = threadIdx.x;
    const int lane = t & 63, w = t >> 6;
    float ssum = 0.f;

    if (w == 0) {
        float v[20]; int id[20];
#pragma unroll
        for (int i = 0; i < 20; ++i) {
            const int e = i * 64 + lane;
            v[i] = cval[e]; id[i] = cidx[e];
        }
        for (int it = 0; it < NGAMMA; ++it) {
            float bv = v[0]; int bi = id[0];
#pragma unroll
            for (int i = 1; i < 20; ++i)
                if (v[i] > bv || (v[i] == bv && id[i] < bi)) { bv = v[i]; bi = id[i]; }
#pragma unroll
            for (int off = 1; off < 64; off <<= 1) {
                const float ov = __shfl_xor(bv, off);
                const int   oi = __shfl_xor(bi, off);
                if (ov > bv || (ov == bv && oi < bi)) { bv = ov; bi = oi; }
            }
            if (lane == 0) sel[it] = bi;
            ssum += bv;
#pragma unroll
            for (int i = 0; i < 20; ++i) if (id[i] == bi) v[i] = -1e30f;
        }
        if (lane < NGAMMA) {
            const int a = sel[lane];   // lane0-written; same-wave LDS ordered
            const float4 pv = ((const float4*)pval)[a];
            float bv = pv.x; int bc = 0;       // ascending c = ascending q-block
            if (pv.y > bv) { bv = pv.y; bc = 1; }
            if (pv.z > bv) { bv = pv.z; bc = 2; }
            if (pv.w > bv) { bv = pv.w; bc = 3; }
            selj[lane] = ((a >> 9) << 9) + pidx[(size_t)a * 4 + bc];
        }
    }
    __syncthreads();

    float acc = 0.f;
    for (int pr = 0; pr < NGAMMA; ++pr) {
        const int a = sel[pr];
        const int j = selj[pr];
        const float* za = z + (size_t)a * ND;
        const float* zj = z + (size_t)j * ND;
        for (int d = t; d < ND; d += 256) {
            const float df = za[d] - zj[d];
            acc = fmaf(df, df, acc);
        }
    }
#pragma unroll
    for (int off = 1; off < 64; off <<= 1) acc += __shfl_xor(acc, off);
    if (lane == 0) red[w] = acc;
    __syncthreads();
    if (t == 0) {
        const float tot = red[0] + red[1] + red[2] + red[3];
        out[0] = 25.0f * tot / (float)(NGAMMA * ND);
        out[1] = ssum / (float)NGAMMA;
    }
}

extern "C" void kernel_launch(void* const* d_in, const int* in_sizes, int n_in,
                              void* d_out, int out_size, void* d_ws, size_t ws_size,
                              hipStream_t stream)
{
    const float* z    = (const float*)d_in[0];
    const int*   view = (const int*)d_in[1];
    float*       out  = (float*)d_out;
    char* ws = (char*)d_ws;

    // layout: zt 48MB | pval 1MB | pidx 1MB | cval | cidx
    const size_t zt_off   = 0;
    const size_t pval_off = (size_t)NB * NP * ND * 2;
    const size_t pidx_off = pval_off + (size_t)NB * NP * 4 * 4;
    const size_t cval_off = pidx_off + (size_t)NB * NP * 4 * 4;
    const size_t cidx_off = cval_off + 64 * NGAMMA * 4;

    unsigned short* zt = (unsigned short*)(ws + zt_off);
    float* pval = (float*)(ws + pval_off);
    int*   pidx = (int*)(ws + pidx_off);
    float* cval = (float*)(ws + cval_off);
    int*   cidx = (int*)(ws + cidx_off);

    fm_convert<<<NB * NKS * 4, 256, 0, stream>>>(z, zt);
    fm_gemm<<<NB * 10, 256, 0, stream>>>(zt, view, pval, pidx);
    fm_topk_local<<<(NB * NP) / 1024, 64, 0, stream>>>(pval, cval, cidx);
    fm_final<<<1, 256, 0, stream>>>(cval, cidx, pval, pidx, z, out);
}

// Round 11
// 132.956 us; speedup vs baseline: 2.0310x; 1.0159x over previous
//
#include <hip/hip_runtime.h>

// FeatureMatchSimpleLoss: B=128, P=512, D=384, GAMMA=20, LAMBDA_INV=25
// R11: gemm -> 8-wave (512-thr) blocks, 64x32 per wave: acc halves -> VGPR~80
// -> 24 waves/CU (2x TLP vs R10's 12) with the proven R8 depth-2/3-buffer/
// counted-vmcnt pipeline. Tail: topk_local+final fused via last-block ticket
// (device-scope atomic + threadfence), removing one launch edge.
//   fm_convert: z fp32 -> zt[b][kt][kg][p][8] bf16 (LDS transpose)
//   fm_gemm:    per (b, upper-tri 128x128 tile), fused row+col argmax
//   fm_tail:    64 blocks local top-20; last block merges -> loss + avg

#define NB 128
#define NP 512
#define ND 384
#define NGAMMA 20
#define NKS 12   // 384/32 k-steps

typedef __attribute__((ext_vector_type(8))) short short8;
typedef __attribute__((ext_vector_type(4))) float f32x4;

__device__ __forceinline__ unsigned short f2bf(float f) {
    unsigned int u = __float_as_uint(f);
    u += 0x7fffu + ((u >> 16) & 1u);   // RNE
    return (unsigned short)(u >> 16);
}

__device__ __forceinline__ void gload16(const void* gptr, void* lptr) {
    __builtin_amdgcn_global_load_lds(
        (const __attribute__((address_space(1))) void*)gptr,
        (__attribute__((address_space(3))) void*)lptr, 16, 0, 0);
}

// ---- convert+tile: z fp32 row-major -> zt[b][kt][kg][p 0..511][8] bf16 ----
__global__ __launch_bounds__(256) void fm_convert(
    const float* __restrict__ z, unsigned short* __restrict__ zt)
{
    __shared__ float ls[128][36];   // pad 36: float4 rows 16B-aligned

    const int tid  = threadIdx.x;
    const int bid  = blockIdx.x;
    const int b    = bid / (NKS * 4);
    const int rem  = bid % (NKS * 4);
    const int kt   = rem >> 2;
    const int pblk = rem & 3;

    const float* zsrc = z + ((size_t)b * NP + pblk * 128) * ND + kt * 32;
#pragma unroll
    for (int i = 0; i < 4; ++i) {
        const int f   = tid + i * 256;
        const int row = f >> 3, c4 = f & 7;
        *(float4*)&ls[row][c4 * 4] = *(const float4*)(zsrc + (size_t)row * ND + c4 * 4);
    }
    __syncthreads();

    const int kg = tid >> 6, lane = tid & 63;
    unsigned short* dst = zt + (((size_t)b * NKS + kt) * 4 + kg) * 4096
                             + (size_t)pblk * 1024;
#pragma unroll
    for (int it = 0; it < 2; ++it) {
        const int row = it * 64 + lane;
        const float4 v0 = *(const float4*)&ls[row][kg * 8];
        const float4 v1 = *(const float4*)&ls[row][kg * 8 + 4];
        short8 s;
        s[0] = (short)f2bf(v0.x); s[1] = (short)f2bf(v0.y);
        s[2] = (short)f2bf(v0.z); s[3] = (short)f2bf(v0.w);
        s[4] = (short)f2bf(v1.x); s[5] = (short)f2bf(v1.y);
        s[6] = (short)f2bf(v1.z); s[7] = (short)f2bf(v1.w);
        *(short8*)(dst + (size_t)row * 8) = s;
    }
}

// ---- 8-wave MFMA GEMM, depth-2 / 3-buffer / 1-barrier-per-step ----
// wave wid: wr = wid>>2 (row half), wc2 = wid&3 (32-col group); 64x32 output.
__global__ __launch_bounds__(512, 4) void fm_gemm(
    const unsigned short* __restrict__ zt, const int* __restrict__ view,
    float* __restrict__ pval, int* __restrict__ pidx)
{
    __shared__ __align__(16) unsigned short Ah[3][4][128][8];   // 24 KB
    __shared__ __align__(16) unsigned short Bh[3][4][128][8];   // 24 KB
    __shared__ int vs[NP];                                      //  2 KB
    // epilogue scratch aliased onto Ah[0] (last reader of buf0 = COMPUTE(kt=9),
    // separated from epilogue by the kt=10 and kt=11 barriers)
    float* lsv = (float*)&Ah[0][0][0][0];   // [2][4][64]  row-side
    int*   lsi = (int*)lsv + 512;
    float* lqv = (float*)lsv + 1024;        // [4][2][32]  col-side
    int*   lqi = (int*)lsv + 1280;

    const int tid  = threadIdx.x;           // 0..511
    const int lane = tid & 63;
    const int wid  = tid >> 6;              // 0..7
    const int wr   = wid >> 2;              // 0..1
    const int wc2  = wid & 3;               // 0..3 (32-col group)
    const int g    = lane >> 4, r = lane & 15;

    // XCD swizzle (1280 % 8 == 0 -> bijective): each XCD gets 16 whole batches
    const int bid  = blockIdx.x;
    const int gidx = (bid & 7) * 160 + (bid >> 3);
    const int b    = gidx / 10;
    const int t    = gidx % 10;
    int tr, tc;
    if (t < 4)      { tr = 0; tc = t; }
    else if (t < 7) { tr = 1; tc = t - 3; }
    else if (t < 9) { tr = 2; tc = t - 5; }
    else            { tr = 3; tc = 3; }
    const bool diag = (tr == tc);
    const int p0 = tr * 128, q0 = tc * 128;

    vs[tid] = view[tid];
    __builtin_amdgcn_sched_barrier(0);

    f32x4 acc[4][2];
#pragma unroll
    for (int mi = 0; mi < 4; ++mi)
#pragma unroll
        for (int ni = 0; ni < 2; ++ni) acc[mi][ni] = (f32x4){0.f, 0.f, 0.f, 0.f};

    // stage one 32-k tile: wave wid does A chunk wid and B chunk wid
    // (kg = wid>>1, rowhalf = (wid&1)*64); each chunk 1KB contiguous in zt.
#define STAGE(BUF, KT)                                                           \
    do {                                                                         \
        const int kg_ = wid >> 1;                                                \
        const int rb_ = (wid & 1) * 64;                                          \
        const size_t pl_ = (((size_t)b * NKS + (KT)) * 4 + kg_) * 4096;          \
        gload16(zt + pl_ + (size_t)(p0 + rb_ + lane) * 8, &Ah[BUF][kg_][rb_][0]); \
        gload16(zt + pl_ + (size_t)(q0 + rb_ + lane) * 8, &Bh[BUF][kg_][rb_][0]); \
    } while (0)

#define COMPUTE(BUF)                                                             \
    do {                                                                         \
        short8 ah_[4], bh_[2];                                                   \
        _Pragma("unroll")                                                        \
        for (int mi = 0; mi < 4; ++mi)                                           \
            ah_[mi] = *(const short8*)&Ah[BUF][g][wr * 64 + mi * 16 + r][0];     \
        _Pragma("unroll")                                                        \
        for (int ni = 0; ni < 2; ++ni)                                           \
            bh_[ni] = *(const short8*)&Bh[BUF][g][wc2 * 32 + ni * 16 + r][0];    \
        _Pragma("unroll")                                                        \
        for (int mi = 0; mi < 4; ++mi)                                           \
            _Pragma("unroll")                                                    \
            for (int ni = 0; ni < 2; ++ni)                                       \
                acc[mi][ni] = __builtin_amdgcn_mfma_f32_16x16x32_bf16(           \
                    ah_[mi], bh_[ni], acc[mi][ni], 0, 0, 0);                     \
    } while (0)

    STAGE(0, 0);
    STAGE(1, 1);
#pragma unroll
    for (int kt = 0; kt < NKS; ++kt) {
        // per-wave in flight: tiles kt + kt+1 (2 loads each) -> wait kt: vmcnt(2)
        if (kt < NKS - 1) asm volatile("s_waitcnt vmcnt(2)" ::: "memory");
        else              asm volatile("s_waitcnt vmcnt(0)" ::: "memory");
        __builtin_amdgcn_s_barrier();      // tile kt resident everywhere;
                                           // compute(kt-1) done -> STAGE buf free
        __builtin_amdgcn_sched_barrier(0);
        if (kt + 2 < NKS) STAGE((kt + 2) % 3, kt + 2);
        __builtin_amdgcn_sched_barrier(0); // stage issues before compute
        COMPUTE(kt % 3);
    }
#undef STAGE
#undef COMPUTE

    // ---- row-side: per row p, masked max/argmax over this wave's 32 cols ----
    // C/D layout: col = lane&15 (r), row = (lane>>4)*4 + j (g,j)
#pragma unroll
    for (int mi = 0; mi < 4; ++mi) {
#pragma unroll
        for (int j = 0; j < 4; ++j) {
            const int prow = p0 + wr * 64 + mi * 16 + g * 4 + j;
            const int rv = vs[prow];
            float bv = -2.0f; int bq = 0;
#pragma unroll
            for (int ni = 0; ni < 2; ++ni) {   // ascending q; strict > keeps smallest
                const int q = q0 + wc2 * 32 + ni * 16 + r;
                const float v = (vs[q] != rv) ? acc[mi][ni][j] : -1.0f;
                if (v > bv) { bv = v; bq = q; }
            }
#pragma unroll
            for (int off = 1; off < 16; off <<= 1) {   // reduce over col-lanes
                const float ov = __shfl_xor(bv, off);
                const int   oq = __shfl_xor(bq, off);
                if (ov > bv || (ov == bv && oq < bq)) { bv = ov; bq = oq; }
            }
            if (r == 0) {
                lsv[(wr * 4 + wc2) * 64 + mi * 16 + g * 4 + j] = bv;
                lsi[(wr * 4 + wc2) * 64 + mi * 16 + g * 4 + j] = bq;
            }
        }
    }
    // ---- col-side (off-diag only): per col q, masked max/argmax over 128 rows ----
    if (!diag) {
#pragma unroll
        for (int ni = 0; ni < 2; ++ni) {
            const int q = q0 + wc2 * 32 + ni * 16 + r;
            const int qv = vs[q];
            float bv = -2.0f; int bp = 0;
#pragma unroll
            for (int mi = 0; mi < 4; ++mi)
#pragma unroll
                for (int j = 0; j < 4; ++j) {   // ascending p within fixed g
                    const int prow = p0 + wr * 64 + mi * 16 + g * 4 + j;
                    const float v = (vs[prow] != qv) ? acc[mi][ni][j] : -1.0f;
                    if (v > bv) { bv = v; bp = prow; }
                }
#pragma unroll
            for (int off = 16; off < 64; off <<= 1) {   // reduce over g groups
                const float ov = __shfl_xor(bv, off);
                const int   op = __shfl_xor(bp, off);
                if (ov > bv || (ov == bv && op < bp)) { bv = ov; bp = op; }
            }
            if (g == 0) {
                lqv[(wc2 * 2 + wr) * 32 + ni * 16 + r] = bv;
                lqi[(wc2 * 2 + wr) * 32 + ni * 16 + r] = bp;
            }
        }
    }
    __syncthreads();
    if (tid < 128) {
        {   // row p0+tid: merge 4 col-groups ascending (ascending q)
            const int hw = tid >> 6, rw = tid & 63;
            float v0 = lsv[(hw * 4 + 0) * 64 + rw]; int i0 = lsi[(hw * 4 + 0) * 64 + rw];
#pragma unroll
            for (int c = 1; c < 4; ++c) {
                const float v1 = lsv[(hw * 4 + c) * 64 + rw];
                const int   i1 = lsi[(hw * 4 + c) * 64 + rw];
                if (v1 > v0) { v0 = v1; i0 = i1; }
            }
            pval[((size_t)b * NP + p0 + tid) * 4 + tc] = v0;
            pidx[((size_t)b * NP + p0 + tid) * 4 + tc] = i0;
        }
        if (!diag) {   // col q0+tid: merge 2 row-halves ascending (ascending p)
            const int cg = tid >> 5, cw = tid & 31;
            float v0 = lqv[(cg * 2 + 0) * 32 + cw]; int i0 = lqi[(cg * 2 + 0) * 32 + cw];
            const float v1 = lqv[(cg * 2 + 1) * 32 + cw];
            const int   i1 = lqi[(cg * 2 + 1) * 32 + cw];
            if (v1 > v0) { v0 = v1; i0 = i1; }
            pval[((size_t)b * NP + q0 + tid) * 4 + tr] = v0;
            pidx[((size_t)b * NP + q0 + tid) * 4 + tr] = i0;
        }
    }
}

// ---- tail: 64 one-wave blocks local top-20; LAST block merges + loss ----
__global__ __launch_bounds__(64) void fm_tail(
    const float* __restrict__ pval, const int* __restrict__ pidx,
    const float* __restrict__ z,
    float* __restrict__ cval, int* __restrict__ cidx,
    int* __restrict__ ticket, float* __restrict__ out)
{
    __shared__ int sel[NGAMMA];
    __shared__ int selj[NGAMMA];

    const int lane = threadIdx.x;
    const int base = blockIdx.x * 1024;
    float v[16]; int id[16];
#pragma unroll
    for (int i = 0; i < 16; ++i) {
        const int a = base + i * 64 + lane;
        const float4 pv = ((const float4*)pval)[a];
        float bv = pv.x;                       // ascending c; strict > keeps first
        if (pv.y > bv) bv = pv.y;
        if (pv.z > bv) bv = pv.z;
        if (pv.w > bv) bv = pv.w;
        v[i] = bv; id[i] = a;
    }
    for (int it = 0; it < NGAMMA; ++it) {
        float bv = v[0]; int bi = id[0];
#pragma unroll
        for (int i = 1; i < 16; ++i)
            if (v[i] > bv || (v[i] == bv && id[i] < bi)) { bv = v[i]; bi = id[i]; }
#pragma unroll
        for (int off = 1; off < 64; off <<= 1) {
            const float ov = __shfl_xor(bv, off);
            const int   oi = __shfl_xor(bi, off);
            if (ov > bv || (ov == bv && oi < bi)) { bv = ov; bi = oi; }
        }
        if (lane == 0) {
            cval[blockIdx.x * NGAMMA + it] = bv;
            cidx[blockIdx.x * NGAMMA + it] = bi;
        }
#pragma unroll
        for (int i = 0; i < 16; ++i) if (id[i] == bi) v[i] = -1e30f;
    }

    // ticket: last block to finish does the merge
    __threadfence();   // release our cval/cidx writes device-wide
    int old = 0;
    if (lane == 0)
        old = __hip_atomic_fetch_add(ticket, 1, __ATOMIC_ACQ_REL, __HIP_MEMORY_SCOPE_AGENT);
    old = __shfl(old, 0);
    if (old != 63) return;
    __threadfence();   // acquire all 64 blocks' writes

    float mv[20]; int mid[20];
#pragma unroll
    for (int i = 0; i < 20; ++i) {
        const int e = i * 64 + lane;
        mv[i] = cval[e]; mid[i] = cidx[e];
    }
    float ssum = 0.f;
    for (int it = 0; it < NGAMMA; ++it) {
        float bv = mv[0]; int bi = mid[0];
#pragma unroll
        for (int i = 1; i < 20; ++i)
            if (mv[i] > bv || (mv[i] == bv && mid[i] < bi)) { bv = mv[i]; bi = mid[i]; }
#pragma unroll
        for (int off = 1; off < 64; off <<= 1) {
            const float ov = __shfl_xor(bv, off);
            const int   oi = __shfl_xor(bi, off);
            if (ov > bv || (ov == bv && oi < bi)) { bv = ov; bi = oi; }
        }
        if (lane == 0) sel[it] = bi;
        ssum += bv;                     // all lanes hold the reduced bv
#pragma unroll
        for (int i = 0; i < 20; ++i) if (mid[i] == bi) mv[i] = -1e30f;
    }
    __syncthreads();
    if (lane < NGAMMA) {               // best-j: argmax over 4 partials
        const int a = sel[lane];
        const float4 pv = ((const float4*)pval)[a];
        float bv = pv.x; int bc = 0;   // ascending c = ascending q-block
        if (pv.y > bv) { bv = pv.y; bc = 1; }
        if (pv.z > bv) { bv = pv.z; bc = 2; }
        if (pv.w > bv) { bv = pv.w; bc = 3; }
        selj[lane] = ((a >> 9) << 9) + pidx[(size_t)a * 4 + bc];
    }
    __syncthreads();

    // loss = 25 * mean((z1 - z2)^2) over 20 x 384 (exact fp32 z)
    float acc = 0.f;
    for (int pr = 0; pr < NGAMMA; ++pr) {
        const int a = sel[pr];
        const int j = selj[pr];
        const float* za = z + (size_t)a * ND;
        const float* zj = z + (size_t)j * ND;
#pragma unroll
        for (int it = 0; it < ND / 64; ++it) {
            const int d = it * 64 + lane;
            const float df = za[d] - zj[d];
            acc = fmaf(df, df, acc);
        }
    }
#pragma unroll
    for (int off = 1; off < 64; off <<= 1) acc += __shfl_xor(acc, off);
    if (lane == 0) {
        out[0] = 25.0f * acc / (float)(NGAMMA * ND);
        out[1] = ssum / (float)NGAMMA;
    }
}

extern "C" void kernel_launch(void* const* d_in, const int* in_sizes, int n_in,
                              void* d_out, int out_size, void* d_ws, size_t ws_size,
                              hipStream_t stream)
{
    const float* z    = (const float*)d_in[0];
    const int*   view = (const int*)d_in[1];
    float*       out  = (float*)d_out;
    char* ws = (char*)d_ws;

    // layout: zt 48MB | pval 1MB | pidx 1MB | cval | cidx | ticket
    const size_t zt_off   = 0;
    const size_t pval_off = (size_t)NB * NP * ND * 2;
    const size_t pidx_off = pval_off + (size_t)NB * NP * 4 * 4;
    const size_t cval_off = pidx_off + (size_t)NB * NP * 4 * 4;
    const size_t cidx_off = cval_off + 64 * NGAMMA * 4;
    const size_t tick_off = cidx_off + 64 * NGAMMA * 4;

    unsigned short* zt = (unsigned short*)(ws + zt_off);
    float* pval = (float*)(ws + pval_off);
    int*   pidx = (int*)(ws + pidx_off);
    float* cval = (float*)(ws + cval_off);
    int*   cidx = (int*)(ws + cidx_off);
    int*   tick = (int*)(ws + tick_off);

    hipMemsetAsync(tick, 0, sizeof(int), stream);
    fm_convert<<<NB * NKS * 4, 256, 0, stream>>>(z, zt);
    fm_gemm<<<NB * 10, 512, 0, stream>>>(zt, view, pval, pidx);
    fm_tail<<<(NB * NP) / 1024, 64, 0, stream>>>(pval, pidx, z, cval, cidx, tick, out);
}